// Round 15
// baseline (161.805 us; speedup 1.0000x reference)
//
#include <hip/hip_runtime.h>
#include <math.h>

#define N_NODES 100000
#define N_EDGES 1600000
#define IN_DIM 128
#define OUT_DIM 64

// ---- coarse bucketing geometry ----
#define BSHIFT 9
#define BSIZE  (1 << BSHIFT)                       // 512 dst per bucket
#define NB     ((N_NODES + BSIZE - 1) >> BSHIFT)   // 196 buckets
#define EDGES_PER_BLK 2048
#define NBLK   ((N_EDGES + EDGES_PER_BLK - 1) / EDGES_PER_BLK)   // 782
#define SCANA_LEN (NB * NBLK)                      // 153272
#define SCANA_ITEMS 2048
#define SCANA_NB ((SCANA_LEN + SCANA_ITEMS - 1) / SCANA_ITEMS)   // 75

#define WH_BLOCKS ((N_NODES + 63) / 64)            // 1563
#define AGG_BLOCKS ((N_NODES * 64 + 255) / 256)    // 25000
#define NORM_BLOCKS ((N_EDGES / 4 + 255) / 256)    // 1563

typedef short short8 __attribute__((ext_vector_type(8)));
typedef float f32x4 __attribute__((ext_vector_type(4)));
typedef float f32x2 __attribute__((ext_vector_type(2)));
typedef int   i32x4 __attribute__((ext_vector_type(4)));

__device__ __forceinline__ unsigned short f2bf(float x) {
    unsigned int u = __float_as_uint(x);
    return (unsigned short)((u + 0x7FFFu + ((u >> 16) & 1u)) >> 16);
}
__device__ __forceinline__ short8 pack_bf16x8(float4 p, float4 q) {
    short8 r;
    r[0] = (short)f2bf(p.x); r[1] = (short)f2bf(p.y);
    r[2] = (short)f2bf(p.z); r[3] = (short)f2bf(p.w);
    r[4] = (short)f2bf(q.x); r[5] = (short)f2bf(q.y);
    r[6] = (short)f2bf(q.z); r[7] = (short)f2bf(q.w);
    return r;
}
// d += a*b (packed 2x f32, dual-rate fp32 path)
__device__ __forceinline__ void pk_fma(f32x2& d, f32x2 a, f32x2 b) {
    asm("v_pk_fma_f32 %0, %1, %2, %0" : "+v"(d) : "v"(a), "v"(b));
}

// K1 (fused, block-specialized): blocks [0, NBLK) = per-(block,bucket) coarse
// histogram; blocks [NBLK, NBLK+WH_BLOCKS) = Wh16 = bf16(h @ W.T) via MFMA +
// fp32-exact s1/s2 (w1/w2 = W^T a1/2 computed per wh-block in LDS).
__global__ __launch_bounds__(256) void k_histwh(const int* __restrict__ dst,
                                                int* __restrict__ hist_t,
                                                const float* __restrict__ h,
                                                const float* __restrict__ W,
                                                const float* __restrict__ a_w,
                                                unsigned short* __restrict__ Wh16,
                                                float* __restrict__ s1,
                                                float* __restrict__ s2) {
    const int tid = threadIdx.x;
    if (blockIdx.x < NBLK) {
        // ---- histogram half ----
        __shared__ int lhist[NB];
        const int blk = blockIdx.x;
        if (tid < NB) lhist[tid] = 0;
        __syncthreads();
        const int e0 = blk * EDGES_PER_BLK;
        #pragma unroll
        for (int j = 0; j < 2; ++j) {
            int e = e0 + (j * 256 + tid) * 4;
            if (e < N_EDGES) {
                int4 d4 = *(const int4*)(dst + e);
                atomicAdd(&lhist[d4.x >> BSHIFT], 1);
                atomicAdd(&lhist[d4.y >> BSHIFT], 1);
                atomicAdd(&lhist[d4.z >> BSHIFT], 1);
                atomicAdd(&lhist[d4.w >> BSHIFT], 1);
            }
        }
        __syncthreads();
        if (tid < NB) hist_t[tid * NBLK + blk] = lhist[tid];
        return;
    }
    // ---- Wh half ----
    __shared__ float w1s[IN_DIM];
    __shared__ float w2s[IN_DIM];
    if (tid < IN_DIM) {
        float r1 = 0.f, r2 = 0.f;
        #pragma unroll 8
        for (int dd = 0; dd < OUT_DIM; ++dd) {
            float wv = W[dd * IN_DIM + tid];        // coalesced over tid
            r1 = fmaf(a_w[dd], wv, r1);
            r2 = fmaf(a_w[OUT_DIM + dd], wv, r2);
        }
        w1s[tid] = r1; w2s[tid] = r2;
    }
    __syncthreads();
    const int wv = tid >> 6;
    const int l  = tid & 63;
    const int g  = l >> 4;
    const int lm = l & 15;
    const int node0 = (blockIdx.x - NBLK) * 64 + wv * 16;
    const int row = node0 + lm;
    const int rowc = (row < N_NODES) ? row : (N_NODES - 1);
    const float* hrow = h + (size_t)rowc * IN_DIM;

    short8 afrag[4];
    float sp1 = 0.f, sp2 = 0.f;
    #pragma unroll
    for (int kt = 0; kt < 4; ++kt) {
        const int k0 = kt * 32 + g * 8;
        float4 p = *(const float4*)(hrow + k0);
        float4 q = *(const float4*)(hrow + k0 + 4);
        float4 u1 = *(const float4*)(w1s + k0);
        float4 v1 = *(const float4*)(w1s + k0 + 4);
        float4 u2 = *(const float4*)(w2s + k0);
        float4 v2 = *(const float4*)(w2s + k0 + 4);
        sp1 += p.x*u1.x + p.y*u1.y + p.z*u1.z + p.w*u1.w
             + q.x*v1.x + q.y*v1.y + q.z*v1.z + q.w*v1.w;
        sp2 += p.x*u2.x + p.y*u2.y + p.z*u2.z + p.w*u2.w
             + q.x*v2.x + q.y*v2.y + q.z*v2.z + q.w*v2.w;
        afrag[kt] = pack_bf16x8(p, q);
    }
    sp1 += __shfl_xor(sp1, 16, 64); sp1 += __shfl_xor(sp1, 32, 64);
    sp2 += __shfl_xor(sp2, 16, 64); sp2 += __shfl_xor(sp2, 32, 64);
    if (l < 16 && row < N_NODES) { s1[row] = sp1; s2[row] = sp2; }

    f32x4 acc[4] = {f32x4{0,0,0,0}, f32x4{0,0,0,0}, f32x4{0,0,0,0}, f32x4{0,0,0,0}};
    #pragma unroll
    for (int nt = 0; nt < 4; ++nt) {
        #pragma unroll
        for (int kt = 0; kt < 4; ++kt) {
            const float* wr = W + (size_t)(nt * 16 + lm) * IN_DIM + kt * 32 + g * 8;
            float4 p = *(const float4*)wr;
            float4 q = *(const float4*)(wr + 4);
            short8 bfrag = pack_bf16x8(p, q);
            acc[nt] = __builtin_amdgcn_mfma_f32_16x16x32_bf16(afrag[kt], bfrag, acc[nt], 0, 0, 0);
        }
    }
    #pragma unroll
    for (int nt = 0; nt < 4; ++nt) {
        #pragma unroll
        for (int r = 0; r < 4; ++r) {
            int nodo = node0 + g * 4 + r;
            if (nodo < N_NODES)
                Wh16[(size_t)nodo * OUT_DIM + nt * 16 + lm] = f2bf(acc[nt][r]);
        }
    }
}

// K2: single-kernel scan (merges part+final): block bid reduces the region
// [0, bid*2048) itself (vectorized, L2-resident), then locally scans its own
// 2048 items. Kills the bsum round-trip and one launch.
__global__ __launch_bounds__(256) void k_scanAll(const int* __restrict__ in,
                                                 int* __restrict__ outscan) {
    __shared__ int red[4];
    __shared__ int wtot[4];
    const int tid = threadIdx.x;
    const int lane = tid & 63;
    const int wid = tid >> 6;
    const int bid = blockIdx.x;
    // 1) sum of everything before this block's slice
    const int preEnd = bid * SCANA_ITEMS;            // multiple of 2048
    int s = 0;
    for (int i = tid * 4; i + 3 < preEnd; i += 1024) {
        int4 a = *(const int4*)(in + i);
        s += a.x + a.y + a.z + a.w;
    }
    #pragma unroll
    for (int off = 32; off > 0; off >>= 1) s += __shfl_xor(s, off, 64);
    if (lane == 0) red[wid] = s;
    __syncthreads();
    const int blockbase = red[0] + red[1] + red[2] + red[3];
    // 2) local exclusive scan of this block's 2048 items (8 per thread)
    const int base = bid * SCANA_ITEMS + tid * 8;
    int c[8];
    if (base + 7 < SCANA_LEN) {
        int4 a = *(const int4*)(in + base);
        int4 b = *(const int4*)(in + base + 4);
        c[0]=a.x; c[1]=a.y; c[2]=a.z; c[3]=a.w;
        c[4]=b.x; c[5]=b.y; c[6]=b.z; c[7]=b.w;
    } else {
        #pragma unroll
        for (int j = 0; j < 8; ++j)
            c[j] = (base + j < SCANA_LEN) ? in[base + j] : 0;
    }
    int tot = 0;
    #pragma unroll
    for (int j = 0; j < 8; ++j) tot += c[j];
    int inc = tot;
    #pragma unroll
    for (int off = 1; off < 64; off <<= 1) {
        int u = __shfl_up(inc, off, 64);
        if (lane >= off) inc += u;
    }
    if (lane == 63) wtot[wid] = inc;
    __syncthreads();
    int wbase = 0;
    #pragma unroll
    for (int w = 0; w < 4; ++w) wbase += (w < wid) ? wtot[w] : 0;
    int run = blockbase + wbase + (inc - tot);
    #pragma unroll
    for (int j = 0; j < 8; ++j) {
        int i = base + j;
        if (i < SCANA_LEN) { outscan[i] = run; run += c[j]; }
    }
}

// K3: per-edge ae + coarse binning into block-private bucket ranges.
// 512 threads (8 waves) for better gather/LDS-atomic latency hiding.
// Record: word0 = src | (dstlocal << 17), word1 = ae bits.
__global__ __launch_bounds__(512) void k_binA(const int* __restrict__ ei,
                                              const float* __restrict__ s1,
                                              const float* __restrict__ s2,
                                              const int* __restrict__ flat_scan,
                                              int2* __restrict__ brec,
                                              float* __restrict__ ae_orig) {
    __shared__ int lbase[NB];
    __shared__ int lcur[NB];
    const int tid = threadIdx.x;
    const int blk = blockIdx.x;
    if (tid < NB) { lbase[tid] = flat_scan[tid * NBLK + blk]; lcur[tid] = 0; }
    __syncthreads();
    const int e = blk * EDGES_PER_BLK + tid * 4;     // 512 threads x 4 = 2048
    if (e < N_EDGES) {
        int4 s4 = *(const int4*)(ei + e);
        int4 d4 = *(const int4*)(ei + N_EDGES + e);
        f32x4 aev;
        #pragma unroll
        for (int q = 0; q < 4; ++q) {
            int src = ((const int*)&s4)[q];
            int dstv = ((const int*)&d4)[q];
            float a = s1[src] + s2[dstv];
            a = (a > 0.f) ? a : 0.2f * a;            // leaky_relu(0.2)
            float ae = expf(a);                       // global-max shift cancels
            aev[q] = ae;
            int b = dstv >> BSHIFT;
            int r = atomicAdd(&lcur[b], 1);           // LDS atomic
            brec[lbase[b] + r] = make_int2(src | ((dstv & (BSIZE - 1)) << 17),
                                           __float_as_int(ae));
        }
        __builtin_nontemporal_store(aev, (f32x4*)(ae_orig + e));
    }
}

// K4: fine sort within each 512-dst bucket (1024 threads for latency hiding):
// LDS hist + scan -> offsets[], dst-sorted (src,ae), per-dst denom -> inv_tab.
__global__ __launch_bounds__(1024) void k_fine(const int2* __restrict__ brec,
                                               const int* __restrict__ flat_scan,
                                               int* __restrict__ offsets,
                                               int2* __restrict__ sa_sorted,
                                               float* __restrict__ inv_tab) {
    __shared__ int lhist[BSIZE];
    __shared__ int lofs[BSIZE];
    __shared__ int lcur[BSIZE];
    __shared__ float lsum[BSIZE];
    __shared__ int wsum[4];
    const int tid = threadIdx.x;
    const int b = blockIdx.x;
    const int base = flat_scan[b * NBLK];
    const int endp = (b + 1 < NB) ? flat_scan[(b + 1) * NBLK] : N_EDGES;
    const int cnt = endp - base;
    if (tid < BSIZE) { lhist[tid] = 0; lsum[tid] = 0.f; }
    __syncthreads();
    for (int i = tid; i < cnt; i += 1024)
        atomicAdd(&lhist[(unsigned)brec[base + i].x >> 17], 1);
    __syncthreads();
    if (tid < 256) {
        const int lane = tid & 63;
        int c0 = lhist[2 * tid], c1 = lhist[2 * tid + 1];
        int s = c0 + c1;
        int inc = s;
        #pragma unroll
        for (int off = 1; off < 64; off <<= 1) {
            int u = __shfl_up(inc, off, 64);
            if (lane >= off) inc += u;
        }
        if (lane == 63) wsum[tid >> 6] = inc;
        lofs[2 * tid] = inc - s;          // pre-wave-base exclusive
        lofs[2 * tid + 1] = c0;           // carry c0
    }
    __syncthreads();
    if (tid < 256) {
        const int wid = tid >> 6;
        int wb = 0;
        #pragma unroll
        for (int w = 0; w < 4; ++w) wb += (w < wid) ? wsum[w] : 0;
        int ex = lofs[2 * tid] + wb;
        int c0 = lofs[2 * tid + 1];
        lofs[2 * tid] = ex; lofs[2 * tid + 1] = ex + c0;
        lcur[2 * tid] = ex; lcur[2 * tid + 1] = ex + c0;
    }
    __syncthreads();
    const int dst0 = b << BSHIFT;
    if (tid < BSIZE) {
        int node = dst0 + tid;
        if (node < N_NODES) offsets[node] = base + lofs[tid];
    }
    if (b == NB - 1 && tid == 0) offsets[N_NODES] = N_EDGES;
    for (int i = tid; i < cnt; i += 1024) {
        int2 rec = brec[base + i];
        int dstl = (unsigned)rec.x >> 17;
        float ae = __int_as_float(rec.y);
        int pos = base + atomicAdd(&lcur[dstl], 1);
        sa_sorted[pos] = make_int2(rec.x & 0x1FFFF, rec.y);
        atomicAdd(&lsum[dstl], ae);
    }
    __syncthreads();
    if (tid < BSIZE) {
        int node = dst0 + tid;
        if (node < N_NODES) inv_tab[node] = 1.f / (lsum[tid] + 1e-9f);
    }
}

// K5 (fused, block-specialized): blocks [0, AGG_BLOCKS) = aggregation
// (one wave per dst node, 8 lanes/edge, pk_fma, distributed ELU epilogue);
// blocks [AGG_BLOCKS, ...) = alpha_norm (x4 vectorized, NT streams).
__global__ __launch_bounds__(256) void k_aggnorm(const int2* __restrict__ sa_sorted,
                                                 const int* __restrict__ offsets,
                                                 const unsigned short* __restrict__ Wh16,
                                                 const float* __restrict__ inv_tab,
                                                 float* __restrict__ out,
                                                 const int* __restrict__ dst_arr,
                                                 const float* __restrict__ ae_orig,
                                                 float* __restrict__ alpha_norm) {
    const int tid = threadIdx.x;
    if (blockIdx.x >= AGG_BLOCKS) {
        int t = (blockIdx.x - AGG_BLOCKS) * 256 + tid;
        if (t >= N_EDGES / 4) return;
        i32x4 d4 = __builtin_nontemporal_load((const i32x4*)dst_arr + t);
        f32x4 a4 = __builtin_nontemporal_load((const f32x4*)ae_orig + t);
        f32x4 r;
        r.x = a4.x * inv_tab[d4.x];
        r.y = a4.y * inv_tab[d4.y];
        r.z = a4.z * inv_tab[d4.z];
        r.w = a4.w * inv_tab[d4.w];
        __builtin_nontemporal_store(r, (f32x4*)alpha_norm + t);
        return;
    }
    const int gid = blockIdx.x * 256 + tid;
    const int node = gid >> 6;
    const int l = gid & 63;
    if (node >= N_NODES) return;
    const int g = l >> 3;       // edge slot 0..7
    const int o = l & 7;        // dim octet 0..7
    const int beg = offsets[node];
    const int end = offsets[node + 1];
    f32x2 acc2[4] = {f32x2{0,0}, f32x2{0,0}, f32x2{0,0}, f32x2{0,0}};
    int i = beg;
    int2 pA, pB;
    bool have = (i + 16 <= end);
    if (have) { pA = sa_sorted[i + g]; pB = sa_sorted[i + 8 + g]; }
    while (have) {
        const int4 rA = *(const int4*)(Wh16 + ((size_t)pA.x << 6) + (o << 3));
        const int4 rB = *(const int4*)(Wh16 + ((size_t)pB.x << 6) + (o << 3));
        const float aeA = __int_as_float(pA.y);
        const float aeB = __int_as_float(pB.y);
        const int inext = i + 16;
        have = (inext + 16 <= end);
        if (have) { pA = sa_sorted[inext + g]; pB = sa_sorted[inext + 8 + g]; }
        i = inext;
        f32x2 a2A = {aeA, aeA}, a2B = {aeB, aeB};
        #pragma unroll
        for (int q = 0; q < 4; ++q) {
            int v = ((const int*)&rA)[q];
            f32x2 f = { __uint_as_float((unsigned)v << 16),
                        __uint_as_float((unsigned)v & 0xFFFF0000u) };
            pk_fma(acc2[q], f, a2A);
        }
        #pragma unroll
        for (int q = 0; q < 4; ++q) {
            int v = ((const int*)&rB)[q];
            f32x2 f = { __uint_as_float((unsigned)v << 16),
                        __uint_as_float((unsigned)v & 0xFFFF0000u) };
            pk_fma(acc2[q], f, a2B);
        }
    }
    for (; i < end; i += 8) {
        int idx = i + g;
        int2 p = (idx < end) ? sa_sorted[idx] : make_int2(0, 0);
        const int4 r = *(const int4*)(Wh16 + ((size_t)p.x << 6) + (o << 3));
        float ae = __int_as_float(p.y);          // 0 for masked lanes
        f32x2 a2 = {ae, ae};
        #pragma unroll
        for (int q = 0; q < 4; ++q) {
            int v = ((const int*)&r)[q];
            f32x2 f = { __uint_as_float((unsigned)v << 16),
                        __uint_as_float((unsigned)v & 0xFFFF0000u) };
            pk_fma(acc2[q], f, a2);
        }
    }
    #pragma unroll
    for (int m = 8; m <= 32; m <<= 1) {
        #pragma unroll
        for (int q = 0; q < 4; ++q) {
            acc2[q].x += __shfl_xor(acc2[q].x, m, 64);
            acc2[q].y += __shfl_xor(acc2[q].y, m, 64);
        }
    }
    // distributed epilogue: lane (g,o) owns output dim o*8+g
    const float inv = inv_tab[node];
    const int q = g >> 1;
    float vx = (q == 0) ? acc2[0].x : (q == 1) ? acc2[1].x : (q == 2) ? acc2[2].x : acc2[3].x;
    float vy = (q == 0) ? acc2[0].y : (q == 1) ? acc2[1].y : (q == 2) ? acc2[2].y : acc2[3].y;
    float x = ((g & 1) ? vy : vx) * inv;
    x = (x > 0.f) ? x : expf(x) - 1.f;
    out[(size_t)node * OUT_DIM + o * 8 + g] = x;
}

extern "C" void kernel_launch(void* const* d_in, const int* in_sizes, int n_in,
                              void* d_out, int out_size, void* d_ws, size_t ws_size,
                              hipStream_t stream) {
    const float* h   = (const float*)d_in[0];
    const float* W   = (const float*)d_in[1];
    const float* a_w = (const float*)d_in[2];
    const int*   ei  = (const int*)d_in[3];    // [2, E]: row0=src, row1=dst

    float* out        = (float*)d_out;                       // [N, 64] elu(out)
    float* alpha_norm = out + (size_t)N_NODES * OUT_DIM;     // [E]

    // workspace layout (~47 MB); 16B-aligned arrays first
    char* ws = (char*)d_ws;
    int2* brec      = (int2*)ws;            ws += (size_t)N_EDGES * 8;
    int2* sa_sorted = (int2*)ws;            ws += (size_t)N_EDGES * 8;
    unsigned short* Wh16 = (unsigned short*)ws;  ws += (size_t)N_NODES * OUT_DIM * 2;
    float* ae_orig  = (float*)ws;           ws += (size_t)N_EDGES * 4;
    float* s1       = (float*)ws;           ws += (size_t)N_NODES * 4;
    float* s2       = (float*)ws;           ws += (size_t)N_NODES * 4;
    int*   hist_t   = (int*)ws;             ws += (size_t)SCANA_LEN * 4;
    int*   flat_scan= (int*)ws;             ws += (size_t)SCANA_LEN * 4;
    int*   offsets  = (int*)ws;             ws += (size_t)(N_NODES + 1) * 4;
    float* inv_tab  = (float*)ws;           ws += (size_t)N_NODES * 4;

    k_histwh<<<NBLK + WH_BLOCKS, 256, 0, stream>>>(ei + N_EDGES, hist_t,
                                                   h, W, a_w, Wh16, s1, s2);
    k_scanAll<<<SCANA_NB, 256, 0, stream>>>(hist_t, flat_scan);
    k_binA<<<NBLK, 512, 0, stream>>>(ei, s1, s2, flat_scan, brec, ae_orig);
    k_fine<<<NB, 1024, 0, stream>>>(brec, flat_scan, offsets, sa_sorted, inv_tab);
    k_aggnorm<<<AGG_BLOCKS + NORM_BLOCKS, 256, 0, stream>>>(sa_sorted, offsets, Wh16,
                                                            inv_tab, out,
                                                            ei + N_EDGES, ae_orig,
                                                            alpha_norm);
}

// Round 16
// 141.695 us; speedup vs baseline: 1.1419x; 1.1419x over previous
//
#include <hip/hip_runtime.h>
#include <math.h>

#define N_NODES 100000
#define N_EDGES 1600000
#define IN_DIM 128
#define OUT_DIM 64

// ---- coarse bucketing geometry ----
#define BSHIFT 9
#define BSIZE  (1 << BSHIFT)                       // 512 dst per bucket
#define NB     ((N_NODES + BSIZE - 1) >> BSHIFT)   // 196 buckets
#define EDGES_PER_BLK 2048
#define NBLK   ((N_EDGES + EDGES_PER_BLK - 1) / EDGES_PER_BLK)   // 782
#define SCANA_LEN (NB * NBLK)                      // 153272
#define SCANA_ITEMS 2048
#define SCANA_NB ((SCANA_LEN + SCANA_ITEMS - 1) / SCANA_ITEMS)   // 75

#define WH_BLOCKS ((N_NODES + 63) / 64)            // 1563
#define AGG_BLOCKS ((N_NODES * 64 + 255) / 256)    // 25000
#define NORM_BLOCKS ((N_EDGES / 4 + 255) / 256)    // 1563

typedef short short8 __attribute__((ext_vector_type(8)));
typedef float f32x4 __attribute__((ext_vector_type(4)));
typedef float f32x2 __attribute__((ext_vector_type(2)));
typedef int   i32x4 __attribute__((ext_vector_type(4)));

__device__ __forceinline__ unsigned short f2bf(float x) {
    unsigned int u = __float_as_uint(x);
    return (unsigned short)((u + 0x7FFFu + ((u >> 16) & 1u)) >> 16);
}
__device__ __forceinline__ short8 pack_bf16x8(float4 p, float4 q) {
    short8 r;
    r[0] = (short)f2bf(p.x); r[1] = (short)f2bf(p.y);
    r[2] = (short)f2bf(p.z); r[3] = (short)f2bf(p.w);
    r[4] = (short)f2bf(q.x); r[5] = (short)f2bf(q.y);
    r[6] = (short)f2bf(q.z); r[7] = (short)f2bf(q.w);
    return r;
}
// d += a*b (packed 2x f32, dual-rate fp32 path)
__device__ __forceinline__ void pk_fma(f32x2& d, f32x2 a, f32x2 b) {
    asm("v_pk_fma_f32 %0, %1, %2, %0" : "+v"(d) : "v"(a), "v"(b));
}

// K1 (fused, block-specialized): blocks [0, NBLK) do the per-(block,bucket)
// coarse histogram; blocks [NBLK, NBLK+WH_BLOCKS) do Wh16 = bf16(h @ W.T)
// via MFMA + fp32-exact s1/s2. The w1/w2 = W^T a1/2 vectors are computed
// PER WH-BLOCK into LDS (128 lanes x 64 FMA, ~trivial) so the two halves
// have no cross-dependency inside one launch.
__global__ __launch_bounds__(256) void k_histwh(const int* __restrict__ dst,
                                                int* __restrict__ hist_t,
                                                const float* __restrict__ h,
                                                const float* __restrict__ W,
                                                const float* __restrict__ a_w,
                                                unsigned short* __restrict__ Wh16,
                                                float* __restrict__ s1,
                                                float* __restrict__ s2) {
    const int tid = threadIdx.x;
    if (blockIdx.x < NBLK) {
        // ---- histogram half ----
        __shared__ int lhist[NB];
        const int blk = blockIdx.x;
        if (tid < NB) lhist[tid] = 0;
        __syncthreads();
        const int e0 = blk * EDGES_PER_BLK;
        #pragma unroll
        for (int j = 0; j < 2; ++j) {
            int e = e0 + (j * 256 + tid) * 4;
            if (e < N_EDGES) {
                int4 d4 = *(const int4*)(dst + e);
                atomicAdd(&lhist[d4.x >> BSHIFT], 1);
                atomicAdd(&lhist[d4.y >> BSHIFT], 1);
                atomicAdd(&lhist[d4.z >> BSHIFT], 1);
                atomicAdd(&lhist[d4.w >> BSHIFT], 1);
            }
        }
        __syncthreads();
        if (tid < NB) hist_t[tid * NBLK + blk] = lhist[tid];
        return;
    }
    // ---- Wh half ----
    __shared__ float w1s[IN_DIM];
    __shared__ float w2s[IN_DIM];
    if (tid < IN_DIM) {
        float r1 = 0.f, r2 = 0.f;
        #pragma unroll 8
        for (int dd = 0; dd < OUT_DIM; ++dd) {
            float wv = W[dd * IN_DIM + tid];        // coalesced over tid
            r1 = fmaf(a_w[dd], wv, r1);
            r2 = fmaf(a_w[OUT_DIM + dd], wv, r2);
        }
        w1s[tid] = r1; w2s[tid] = r2;
    }
    __syncthreads();
    const int wv = tid >> 6;
    const int l  = tid & 63;
    const int g  = l >> 4;
    const int lm = l & 15;
    const int node0 = (blockIdx.x - NBLK) * 64 + wv * 16;
    const int row = node0 + lm;
    const int rowc = (row < N_NODES) ? row : (N_NODES - 1);
    const float* hrow = h + (size_t)rowc * IN_DIM;

    short8 afrag[4];
    float sp1 = 0.f, sp2 = 0.f;
    #pragma unroll
    for (int kt = 0; kt < 4; ++kt) {
        const int k0 = kt * 32 + g * 8;
        float4 p = *(const float4*)(hrow + k0);
        float4 q = *(const float4*)(hrow + k0 + 4);
        float4 u1 = *(const float4*)(w1s + k0);
        float4 v1 = *(const float4*)(w1s + k0 + 4);
        float4 u2 = *(const float4*)(w2s + k0);
        float4 v2 = *(const float4*)(w2s + k0 + 4);
        sp1 += p.x*u1.x + p.y*u1.y + p.z*u1.z + p.w*u1.w
             + q.x*v1.x + q.y*v1.y + q.z*v1.z + q.w*v1.w;
        sp2 += p.x*u2.x + p.y*u2.y + p.z*u2.z + p.w*u2.w
             + q.x*v2.x + q.y*v2.y + q.z*v2.z + q.w*v2.w;
        afrag[kt] = pack_bf16x8(p, q);
    }
    sp1 += __shfl_xor(sp1, 16, 64); sp1 += __shfl_xor(sp1, 32, 64);
    sp2 += __shfl_xor(sp2, 16, 64); sp2 += __shfl_xor(sp2, 32, 64);
    if (l < 16 && row < N_NODES) { s1[row] = sp1; s2[row] = sp2; }

    f32x4 acc[4] = {f32x4{0,0,0,0}, f32x4{0,0,0,0}, f32x4{0,0,0,0}, f32x4{0,0,0,0}};
    #pragma unroll
    for (int nt = 0; nt < 4; ++nt) {
        #pragma unroll
        for (int kt = 0; kt < 4; ++kt) {
            const float* wr = W + (size_t)(nt * 16 + lm) * IN_DIM + kt * 32 + g * 8;
            float4 p = *(const float4*)wr;
            float4 q = *(const float4*)(wr + 4);
            short8 bfrag = pack_bf16x8(p, q);
            acc[nt] = __builtin_amdgcn_mfma_f32_16x16x32_bf16(afrag[kt], bfrag, acc[nt], 0, 0, 0);
        }
    }
    #pragma unroll
    for (int nt = 0; nt < 4; ++nt) {
        #pragma unroll
        for (int r = 0; r < 4; ++r) {
            int nodo = node0 + g * 4 + r;
            if (nodo < N_NODES)
                Wh16[(size_t)nodo * OUT_DIM + nt * 16 + lm] = f2bf(acc[nt][r]);
        }
    }
}

// K2a: per-block partial sums (2048 items / block, 8 per thread).
__global__ __launch_bounds__(256) void k_scanA_part(const int* __restrict__ in,
                                                    int* __restrict__ bsum) {
    __shared__ int wsum[4];
    const int tid = threadIdx.x;
    const int base = blockIdx.x * SCANA_ITEMS + tid * 8;
    int s = 0;
    if (base + 7 < SCANA_LEN) {
        int4 a = *(const int4*)(in + base);
        int4 b = *(const int4*)(in + base + 4);
        s = a.x + a.y + a.z + a.w + b.x + b.y + b.z + b.w;
    } else {
        for (int j = 0; j < 8; ++j)
            if (base + j < SCANA_LEN) s += in[base + j];
    }
    #pragma unroll
    for (int off = 32; off > 0; off >>= 1) s += __shfl_xor(s, off, 64);
    if ((tid & 63) == 0) wsum[tid >> 6] = s;
    __syncthreads();
    if (tid == 0) bsum[blockIdx.x] = wsum[0] + wsum[1] + wsum[2] + wsum[3];
}

// K2b: final scan; every block redundantly scans the 75 block sums in LDS.
__global__ __launch_bounds__(256) void k_scanA_final(const int* __restrict__ in,
                                                     const int* __restrict__ bsum,
                                                     int* __restrict__ outscan) {
    __shared__ int sb[256];
    __shared__ int wtot[4];
    const int tid = threadIdx.x;
    const int lane = tid & 63;
    const int wid = tid >> 6;
    sb[tid] = (tid < SCANA_NB) ? bsum[tid] : 0;
    __syncthreads();
    #pragma unroll
    for (int off = 1; off < 256; off <<= 1) {
        int u = (tid >= off) ? sb[tid - off] : 0;
        __syncthreads();
        sb[tid] += u;
        __syncthreads();
    }
    const int blockbase = (blockIdx.x > 0) ? sb[blockIdx.x - 1] : 0;
    const int base = blockIdx.x * SCANA_ITEMS + tid * 8;
    int c[8];
    if (base + 7 < SCANA_LEN) {
        int4 a = *(const int4*)(in + base);
        int4 b = *(const int4*)(in + base + 4);
        c[0]=a.x; c[1]=a.y; c[2]=a.z; c[3]=a.w;
        c[4]=b.x; c[5]=b.y; c[6]=b.z; c[7]=b.w;
    } else {
        #pragma unroll
        for (int j = 0; j < 8; ++j)
            c[j] = (base + j < SCANA_LEN) ? in[base + j] : 0;
    }
    int tot = 0;
    #pragma unroll
    for (int j = 0; j < 8; ++j) tot += c[j];
    int inc = tot;
    #pragma unroll
    for (int off = 1; off < 64; off <<= 1) {
        int u = __shfl_up(inc, off, 64);
        if (lane >= off) inc += u;
    }
    if (lane == 63) wtot[wid] = inc;
    __syncthreads();
    int wbase = 0;
    #pragma unroll
    for (int w = 0; w < 4; ++w) wbase += (w < wid) ? wtot[w] : 0;
    int run = blockbase + wbase + (inc - tot);
    #pragma unroll
    for (int j = 0; j < 8; ++j) {
        int i = base + j;
        if (i < SCANA_LEN) { outscan[i] = run; run += c[j]; }
    }
}

// K3: per-edge ae + coarse binning into block-private bucket ranges.
// Record: word0 = src | (dstlocal << 17), word1 = ae bits.
__global__ __launch_bounds__(256) void k_binA(const int* __restrict__ ei,
                                              const float* __restrict__ s1,
                                              const float* __restrict__ s2,
                                              const int* __restrict__ flat_scan,
                                              int2* __restrict__ brec,
                                              float* __restrict__ ae_orig) {
    __shared__ int lbase[NB];
    __shared__ int lcur[NB];
    const int tid = threadIdx.x;
    const int blk = blockIdx.x;
    if (tid < NB) { lbase[tid] = flat_scan[tid * NBLK + blk]; lcur[tid] = 0; }
    __syncthreads();
    const int e0 = blk * EDGES_PER_BLK;
    #pragma unroll
    for (int j = 0; j < 2; ++j) {
        int e = e0 + (j * 256 + tid) * 4;
        if (e >= N_EDGES) continue;
        int4 s4 = *(const int4*)(ei + e);
        int4 d4 = *(const int4*)(ei + N_EDGES + e);
        f32x4 aev;
        #pragma unroll
        for (int q = 0; q < 4; ++q) {
            int src = ((const int*)&s4)[q];
            int dst = ((const int*)&d4)[q];
            float a = s1[src] + s2[dst];
            a = (a > 0.f) ? a : 0.2f * a;            // leaky_relu(0.2)
            float ae = expf(a);                       // global-max shift cancels
            aev[q] = ae;
            int b = dst >> BSHIFT;
            int r = atomicAdd(&lcur[b], 1);           // LDS atomic
            brec[lbase[b] + r] = make_int2(src | ((dst & (BSIZE - 1)) << 17),
                                           __float_as_int(ae));
        }
        __builtin_nontemporal_store(aev, (f32x4*)(ae_orig + e));
    }
}

// K4: fine sort within each 512-dst bucket (1024 threads for latency hiding):
// LDS hist + scan -> offsets[], dst-sorted (src,ae), per-dst denom -> inv_tab.
__global__ __launch_bounds__(1024) void k_fine(const int2* __restrict__ brec,
                                               const int* __restrict__ flat_scan,
                                               int* __restrict__ offsets,
                                               int2* __restrict__ sa_sorted,
                                               float* __restrict__ inv_tab) {
    __shared__ int lhist[BSIZE];
    __shared__ int lofs[BSIZE];
    __shared__ int lcur[BSIZE];
    __shared__ float lsum[BSIZE];
    __shared__ int wsum[4];
    const int tid = threadIdx.x;
    const int b = blockIdx.x;
    const int base = flat_scan[b * NBLK];
    const int endp = (b + 1 < NB) ? flat_scan[(b + 1) * NBLK] : N_EDGES;
    const int cnt = endp - base;
    if (tid < BSIZE) { lhist[tid] = 0; lsum[tid] = 0.f; }
    __syncthreads();
    for (int i = tid; i < cnt; i += 1024)
        atomicAdd(&lhist[(unsigned)brec[base + i].x >> 17], 1);
    __syncthreads();
    if (tid < 256) {
        const int lane = tid & 63;
        int c0 = lhist[2 * tid], c1 = lhist[2 * tid + 1];
        int s = c0 + c1;
        int inc = s;
        #pragma unroll
        for (int off = 1; off < 64; off <<= 1) {
            int u = __shfl_up(inc, off, 64);
            if (lane >= off) inc += u;
        }
        if (lane == 63) wsum[tid >> 6] = inc;
        lofs[2 * tid] = inc - s;          // pre-wave-base exclusive
        lofs[2 * tid + 1] = c0;           // carry c0
    }
    __syncthreads();
    if (tid < 256) {
        const int wid = tid >> 6;
        int wb = 0;
        #pragma unroll
        for (int w = 0; w < 4; ++w) wb += (w < wid) ? wsum[w] : 0;
        int ex = lofs[2 * tid] + wb;
        int c0 = lofs[2 * tid + 1];
        lofs[2 * tid] = ex; lofs[2 * tid + 1] = ex + c0;
        lcur[2 * tid] = ex; lcur[2 * tid + 1] = ex + c0;
    }
    __syncthreads();
    const int dst0 = b << BSHIFT;
    if (tid < BSIZE) {
        int node = dst0 + tid;
        if (node < N_NODES) offsets[node] = base + lofs[tid];
    }
    if (b == NB - 1 && tid == 0) offsets[N_NODES] = N_EDGES;
    for (int i = tid; i < cnt; i += 1024) {
        int2 rec = brec[base + i];
        int dstl = (unsigned)rec.x >> 17;
        float ae = __int_as_float(rec.y);
        int pos = base + atomicAdd(&lcur[dstl], 1);
        sa_sorted[pos] = make_int2(rec.x & 0x1FFFF, rec.y);
        atomicAdd(&lsum[dstl], ae);
    }
    __syncthreads();
    if (tid < BSIZE) {
        int node = dst0 + tid;
        if (node < N_NODES) inv_tab[node] = 1.f / (lsum[tid] + 1e-9f);
    }
}

// K5 (fused, block-specialized): blocks [0, AGG_BLOCKS) = aggregation
// (one wave per dst node, 8 lanes/edge, pk_fma, distributed ELU epilogue:
// after the slot-fold every lane owns ONE output dim -> 1 expf + one
// coalesced 256B wave store);
// blocks [AGG_BLOCKS, ...) = alpha_norm (x4 vectorized, NT streams).
__global__ __launch_bounds__(256) void k_aggnorm(const int2* __restrict__ sa_sorted,
                                                 const int* __restrict__ offsets,
                                                 const unsigned short* __restrict__ Wh16,
                                                 const float* __restrict__ inv_tab,
                                                 float* __restrict__ out,
                                                 const int* __restrict__ dst_arr,
                                                 const float* __restrict__ ae_orig,
                                                 float* __restrict__ alpha_norm) {
    const int tid = threadIdx.x;
    if (blockIdx.x >= AGG_BLOCKS) {
        // ---- alpha_norm half ----
        int t = (blockIdx.x - AGG_BLOCKS) * 256 + tid;
        if (t >= N_EDGES / 4) return;
        i32x4 d4 = __builtin_nontemporal_load((const i32x4*)dst_arr + t);
        f32x4 a4 = __builtin_nontemporal_load((const f32x4*)ae_orig + t);
        f32x4 r;
        r.x = a4.x * inv_tab[d4.x];
        r.y = a4.y * inv_tab[d4.y];
        r.z = a4.z * inv_tab[d4.z];
        r.w = a4.w * inv_tab[d4.w];
        __builtin_nontemporal_store(r, (f32x4*)alpha_norm + t);
        return;
    }
    // ---- aggregation half ----
    const int gid = blockIdx.x * 256 + tid;
    const int node = gid >> 6;
    const int l = gid & 63;
    if (node >= N_NODES) return;
    const int g = l >> 3;       // edge slot 0..7
    const int o = l & 7;        // dim octet 0..7
    const int beg = offsets[node];
    const int end = offsets[node + 1];
    f32x2 acc2[4] = {f32x2{0,0}, f32x2{0,0}, f32x2{0,0}, f32x2{0,0}};
    int i = beg;
    int2 pA, pB;
    bool have = (i + 16 <= end);
    if (have) { pA = sa_sorted[i + g]; pB = sa_sorted[i + 8 + g]; }
    while (have) {
        const int4 rA = *(const int4*)(Wh16 + ((size_t)pA.x << 6) + (o << 3));
        const int4 rB = *(const int4*)(Wh16 + ((size_t)pB.x << 6) + (o << 3));
        const float aeA = __int_as_float(pA.y);
        const float aeB = __int_as_float(pB.y);
        const int inext = i + 16;
        have = (inext + 16 <= end);
        if (have) { pA = sa_sorted[inext + g]; pB = sa_sorted[inext + 8 + g]; }
        i = inext;
        f32x2 a2A = {aeA, aeA}, a2B = {aeB, aeB};
        #pragma unroll
        for (int q = 0; q < 4; ++q) {
            int v = ((const int*)&rA)[q];
            f32x2 f = { __uint_as_float((unsigned)v << 16),
                        __uint_as_float((unsigned)v & 0xFFFF0000u) };
            pk_fma(acc2[q], f, a2A);
        }
        #pragma unroll
        for (int q = 0; q < 4; ++q) {
            int v = ((const int*)&rB)[q];
            f32x2 f = { __uint_as_float((unsigned)v << 16),
                        __uint_as_float((unsigned)v & 0xFFFF0000u) };
            pk_fma(acc2[q], f, a2B);
        }
    }
    for (; i < end; i += 8) {
        int idx = i + g;
        int2 p = (idx < end) ? sa_sorted[idx] : make_int2(0, 0);
        const int4 r = *(const int4*)(Wh16 + ((size_t)p.x << 6) + (o << 3));
        float ae = __int_as_float(p.y);          // 0 for masked lanes
        f32x2 a2 = {ae, ae};
        #pragma unroll
        for (int q = 0; q < 4; ++q) {
            int v = ((const int*)&r)[q];
            f32x2 f = { __uint_as_float((unsigned)v << 16),
                        __uint_as_float((unsigned)v & 0xFFFF0000u) };
            pk_fma(acc2[q], f, a2);
        }
    }
    #pragma unroll
    for (int m = 8; m <= 32; m <<= 1) {
        #pragma unroll
        for (int q = 0; q < 4; ++q) {
            acc2[q].x += __shfl_xor(acc2[q].x, m, 64);
            acc2[q].y += __shfl_xor(acc2[q].y, m, 64);
        }
    }
    // distributed epilogue: lane (g,o) owns output dim o*8+g
    const float inv = inv_tab[node];
    const int q = g >> 1;
    float vx = (q == 0) ? acc2[0].x : (q == 1) ? acc2[1].x : (q == 2) ? acc2[2].x : acc2[3].x;
    float vy = (q == 0) ? acc2[0].y : (q == 1) ? acc2[1].y : (q == 2) ? acc2[2].y : acc2[3].y;
    float x = ((g & 1) ? vy : vx) * inv;
    x = (x > 0.f) ? x : expf(x) - 1.f;
    out[(size_t)node * OUT_DIM + o * 8 + g] = x;
}

extern "C" void kernel_launch(void* const* d_in, const int* in_sizes, int n_in,
                              void* d_out, int out_size, void* d_ws, size_t ws_size,
                              hipStream_t stream) {
    const float* h   = (const float*)d_in[0];
    const float* W   = (const float*)d_in[1];
    const float* a_w = (const float*)d_in[2];
    const int*   ei  = (const int*)d_in[3];    // [2, E]: row0=src, row1=dst

    float* out        = (float*)d_out;                       // [N, 64] elu(out)
    float* alpha_norm = out + (size_t)N_NODES * OUT_DIM;     // [E]

    // workspace layout (~47 MB); 16B-aligned arrays first
    char* ws = (char*)d_ws;
    int2* brec      = (int2*)ws;            ws += (size_t)N_EDGES * 8;
    int2* sa_sorted = (int2*)ws;            ws += (size_t)N_EDGES * 8;
    unsigned short* Wh16 = (unsigned short*)ws;  ws += (size_t)N_NODES * OUT_DIM * 2;
    float* ae_orig  = (float*)ws;           ws += (size_t)N_EDGES * 4;
    float* s1       = (float*)ws;           ws += (size_t)N_NODES * 4;
    float* s2       = (float*)ws;           ws += (size_t)N_NODES * 4;
    int*   hist_t   = (int*)ws;             ws += (size_t)SCANA_LEN * 4;
    int*   flat_scan= (int*)ws;             ws += (size_t)SCANA_LEN * 4;
    int*   bsum     = (int*)ws;             ws += (size_t)SCANA_NB * 4;
    int*   offsets  = (int*)ws;             ws += (size_t)(N_NODES + 1) * 4;
    float* inv_tab  = (float*)ws;           ws += (size_t)N_NODES * 4;

    k_histwh<<<NBLK + WH_BLOCKS, 256, 0, stream>>>(ei + N_EDGES, hist_t,
                                                   h, W, a_w, Wh16, s1, s2);
    k_scanA_part<<<SCANA_NB, 256, 0, stream>>>(hist_t, bsum);
    k_scanA_final<<<SCANA_NB, 256, 0, stream>>>(hist_t, bsum, flat_scan);
    k_binA<<<NBLK, 256, 0, stream>>>(ei, s1, s2, flat_scan, brec, ae_orig);
    k_fine<<<NB, 1024, 0, stream>>>(brec, flat_scan, offsets, sa_sorted, inv_tab);
    k_aggnorm<<<AGG_BLOCKS + NORM_BLOCKS, 256, 0, stream>>>(sa_sorted, offsets, Wh16,
                                                            inv_tab, out,
                                                            ei + N_EDGES, ae_orig,
                                                            alpha_norm);
}